// Round 4
// baseline (574.329 us; speedup 1.0000x reference)
//
#include <hip/hip_runtime.h>
#include <cstdint>
#include <cstddef>

#define Nn 40000
#define Ne 640000
#define CC 128
#define EPSbn 1e-5f

typedef __attribute__((ext_vector_type(8))) __bf16 bf16x8;
typedef __attribute__((ext_vector_type(4))) float floatx4;

__device__ inline unsigned short f2bf(float x){
  union { float f; unsigned u; } c; c.f = x;
  unsigned r = c.u + 0x7fffu + ((c.u >> 16) & 1u);
  return (unsigned short)(r >> 16);
}
__device__ inline float bflo(unsigned u){ return __uint_as_float(u << 16); }
__device__ inline float bfhi(unsigned u){ return __uint_as_float(u & 0xffff0000u); }

// ---------------- zero ----------------
__global__ void zero_k(int* __restrict__ p, int n){
  int i = blockIdx.x*blockDim.x + threadIdx.x;
  if (i < n) p[i] = 0;
}

// ---------------- MFMA bf16 GEMM (z-batched): C = act(A' @ W^T + bias + res') ----------------
// outmode: 0=f32, 1=bf16 row-major, 2=KV interleave K-phase, 3=KV interleave V-phase
struct GA3 {
  const void* A0; const void* A1; const void* A2;
  const float* W0; const float* W1; const float* W2;
  void* C0; void* C1; void* C2;
  int m0, m1, m2;
};

template<int KTILES,bool ABF16,bool HASBIAS,bool HASRES,bool RELU,bool AFFA,bool AFFRES,bool BNSTAT>
__global__ __launch_bounds__(256,2) void mgemm_k(
    GA3 ga, const float* __restrict__ bias, const float* __restrict__ res,
    const float* __restrict__ sc, const float* __restrict__ sh,
    float* __restrict__ bnS, float* __restrict__ bnQ,
    int M, int Ncols)
{
  constexpr int K = KTILES * 128;
  __shared__ __align__(16) unsigned short As[128*136];  // +8 pad: 2-way alias (free)
  __shared__ __align__(16) unsigned short Ws[128*136];
  const int z = blockIdx.z;
  const void*  Ap = (z==0) ? ga.A0 : (z==1) ? ga.A1 : ga.A2;
  const float* W  = (z==0) ? ga.W0 : (z==1) ? ga.W1 : ga.W2;
  void*        Cp = (z==0) ? ga.C0 : (z==1) ? ga.C1 : ga.C2;
  const int mode  = (z==0) ? ga.m0 : (z==1) ? ga.m1 : ga.m2;

  const int tid  = threadIdx.x;
  const int lane = tid & 63;
  const int wv   = tid >> 6;
  const int m    = lane & 15;
  const int quad = lane >> 4;
  const int row0 = blockIdx.x * 128;
  const int col0 = blockIdx.y * 128;
  floatx4 acc[2][8] = {};

  for (int kt = 0; kt < K; kt += 128) {
    #pragma unroll 4
    for (int it = 0; it < 16; ++it) {
      int s = tid + it*256;        // 0..4095
      int r = s >> 5;              // 0..127
      int c = (s & 31) << 2;       // 0..124
      int gr = row0 + r; if (gr >= M) gr = M - 1;
      ushort4 ua;
      if (ABF16) {
        ua = *(const ushort4*)((const unsigned short*)Ap + (size_t)gr*K + kt + c);
      } else {
        float4 a4 = *(const float4*)((const float*)Ap + (size_t)gr*K + kt + c);
        if (AFFA) {
          int kk = kt + c;
          a4.x = a4.x*sc[kk  ] + sh[kk  ];
          a4.y = a4.y*sc[kk+1] + sh[kk+1];
          a4.z = a4.z*sc[kk+2] + sh[kk+2];
          a4.w = a4.w*sc[kk+3] + sh[kk+3];
        }
        ua.x = f2bf(a4.x); ua.y = f2bf(a4.y); ua.z = f2bf(a4.z); ua.w = f2bf(a4.w);
      }
      *(ushort4*)&As[r*136 + c] = ua;
      float4 w4 = *(const float4*)(W + (size_t)(col0 + r)*K + kt + c);
      ushort4 uw;
      uw.x = f2bf(w4.x); uw.y = f2bf(w4.y); uw.z = f2bf(w4.z); uw.w = f2bf(w4.w);
      *(ushort4*)&Ws[r*136 + c] = uw;
    }
    __syncthreads();
    #pragma unroll
    for (int ks = 0; ks < 4; ++ks) {
      int ko = ks*32 + quad*8;
      bf16x8 a0 = *(const bf16x8*)&As[(32*wv      + m)*136 + ko];
      bf16x8 a1 = *(const bf16x8*)&As[(32*wv + 16 + m)*136 + ko];
      #pragma unroll
      for (int j = 0; j < 8; ++j) {
        bf16x8 bj = *(const bf16x8*)&Ws[(16*j + m)*136 + ko];
        acc[0][j] = __builtin_amdgcn_mfma_f32_16x16x32_bf16(a0, bj, acc[0][j], 0, 0, 0);
        acc[1][j] = __builtin_amdgcn_mfma_f32_16x16x32_bf16(a1, bj, acc[1][j], 0, 0, 0);
      }
    }
    __syncthreads();
  }

  float bcol[8], scv[8], shv[8];
  #pragma unroll
  for (int j = 0; j < 8; ++j) {
    int gcol = col0 + 16*j + m;
    if (HASBIAS) bcol[j] = bias[gcol];
    if (AFFRES) { scv[j] = sc[gcol]; shv[j] = sh[gcol]; }
  }
  float ps[8] = {}, pq[8] = {};
  #pragma unroll
  for (int rt = 0; rt < 2; ++rt) {
    #pragma unroll
    for (int rg = 0; rg < 4; ++rg) {
      int grow = row0 + 32*wv + 16*rt + quad*4 + rg;
      if (grow < M) {
        #pragma unroll
        for (int j = 0; j < 8; ++j) {
          int gcol = col0 + 16*j + m;
          float o = acc[rt][j][rg];
          if (HASBIAS) o += bcol[j];
          if (HASRES) {
            float rr = res[(size_t)grow*Ncols + gcol];
            if (AFFRES) rr = rr*scv[j] + shv[j];
            o += rr;
          }
          if (RELU) o = fmaxf(o, 0.f);
          if (BNSTAT) { ps[j] += o; pq[j] += o*o; }
          if (mode == 0)      ((float*)Cp)[(size_t)grow*Ncols + gcol] = o;
          else if (mode == 1) ((unsigned short*)Cp)[(size_t)grow*Ncols + gcol] = f2bf(o);
          else {
            int ph = mode - 2;
            *(unsigned short*)((char*)Cp + (size_t)grow*512 + (gcol>>1)*8 + ph*4 + (gcol&1)*2) = f2bf(o);
          }
        }
      }
    }
  }
  if (BNSTAT) {
    float* sS = (float*)&As[0];        // reuse LDS: 4 waves x 128 cols
    float* sQ = sS + 4*128;
    #pragma unroll
    for (int j = 0; j < 8; ++j) {
      float s = ps[j], qq = pq[j];
      s += __shfl_xor(s, 16); qq += __shfl_xor(qq, 16);
      s += __shfl_xor(s, 32); qq += __shfl_xor(qq, 32);
      if (quad == 0) { sS[wv*128 + 16*j + m] = s; sQ[wv*128 + 16*j + m] = qq; }
    }
    __syncthreads();
    if (wv == 0) {
      #pragma unroll
      for (int c = 0; c < 128; c += 64) {
        int cc = c + lane;
        float s  = sS[cc] + sS[128+cc] + sS[256+cc] + sS[384+cc];
        float qq = sQ[cc] + sQ[128+cc] + sQ[256+cc] + sQ[384+cc];
        atomicAdd(&bnS[col0 + cc], s);
        atomicAdd(&bnQ[col0 + cc], qq);
      }
    }
  }
}

// ---------------- per-edge bias -> CSR-ordered bf16 table ----------------
__global__ __launch_bounds__(256) void ebias_k(
    const float* __restrict__ ef, const float* __restrict__ We,
    const float* __restrict__ be, const int* __restrict__ pos,
    unsigned short* __restrict__ EBs)
{
  __shared__ float efs[32][68];
  __shared__ float Wes[8][68];
  __shared__ float bes[8];
  int tid = threadIdx.x;
  if (tid < 8) bes[tid] = be[tid];
  for (int i = tid; i < 512; i += 256) Wes[i>>6][i&63] = We[i];
  int e0 = blockIdx.x * 32;
  #pragma unroll
  for (int l = 0; l < 2; ++l) {
    int idx = tid + l*256;
    int r   = idx >> 4;
    int q4  = (idx & 15) << 2;
    float4 t = *(const float4*)(ef + (size_t)(e0 + r)*64 + q4);
    efs[r][q4]=t.x; efs[r][q4+1]=t.y; efs[r][q4+2]=t.z; efs[r][q4+3]=t.w;
  }
  __syncthreads();
  int h = tid & 7, el = tid >> 3;
  int e = e0 + el;
  float es = 0.f;
  #pragma unroll
  for (int kk = 0; kk < 64; kk += 4) {
    float4 a = *(const float4*)&efs[el][kk];
    float4 b = *(const float4*)&Wes[h][kk];
    es += a.x*b.x + a.y*b.y + a.z*b.z + a.w*b.w;
  }
  EBs[(size_t)pos[e]*8 + h] = f2bf(es + bes[h]);
}

// ---------------- CSR build ----------------
__global__ void hist_k(const int* __restrict__ dst, int* __restrict__ counts, int E){
  int i = blockIdx.x*blockDim.x + threadIdx.x;
  if (i < E) atomicAdd(&counts[dst[i]], 1);
}

__global__ __launch_bounds__(256) void scan1_k(
    const int* __restrict__ counts, int* __restrict__ part,
    int* __restrict__ bsums, int n)
{
  int tid = threadIdx.x;
  int base = blockIdx.x*1024 + tid*4;
  int v0 = (base   < n) ? counts[base  ] : 0;
  int v1 = (base+1 < n) ? counts[base+1] : 0;
  int v2 = (base+2 < n) ? counts[base+2] : 0;
  int v3 = (base+3 < n) ? counts[base+3] : 0;
  int t1 = v0+v1, t2 = t1+v2, t3 = t2+v3;
  int lane = tid & 63, wv = tid >> 6;
  int x = t3;
  #pragma unroll
  for (int off = 1; off < 64; off <<= 1) {
    int y = __shfl_up(x, off);
    if (lane >= off) x += y;
  }
  __shared__ int wt[4];
  if (lane == 63) wt[wv] = x;
  __syncthreads();
  int wbase = 0;
  #pragma unroll
  for (int w = 0; w < 4; ++w) if (w < wv) wbase += wt[w];
  int excl = wbase + x - t3;
  if (base   < n) part[base  ] = excl;
  if (base+1 < n) part[base+1] = excl + v0;
  if (base+2 < n) part[base+2] = excl + t1;
  if (base+3 < n) part[base+3] = excl + t2;
  if (tid == 255) bsums[blockIdx.x] = wbase + x;
}

__global__ void scan2_k(int* bsums, int nb){
  int lane = threadIdx.x;
  int v = (lane < nb) ? bsums[lane] : 0;
  int x = v;
  #pragma unroll
  for (int off = 1; off < 64; off <<= 1) {
    int y = __shfl_up(x, off);
    if (lane >= off) x += y;
  }
  if (lane < nb) bsums[lane] = x - v;   // exclusive
}

__global__ void scan3_k(int* __restrict__ offsets, const int* __restrict__ bsums,
                        int* __restrict__ cursor, int n, int E){
  int i = blockIdx.x*blockDim.x + threadIdx.x;
  if (i < n) {
    int o = offsets[i] + bsums[i >> 10];
    offsets[i] = o;
    cursor[i]  = o;
  }
  if (i == 0) offsets[n] = E;
}

__global__ void scatter_k(const int* __restrict__ dst, const int* __restrict__ src,
                          int* __restrict__ cursor, int* __restrict__ pos,
                          int* __restrict__ srcs, int E){
  int i = blockIdx.x*blockDim.x + threadIdx.x;
  if (i < E) {
    int p = atomicAdd(&cursor[dst[i]], 1);
    pos[i]  = p;
    srcs[p] = src[i];
  }
}

// ---------------- fused scores + segment softmax + aggregation ----------------
// One wave per dst node; lane l holds channels {2l,2l+1}; head = l>>3.
// KV row: dword 2l = K[2l..2l+1] bf16, dword 2l+1 = V[2l..2l+1] bf16 (uint2/lane).
__global__ __launch_bounds__(256) void agg_k(
    const unsigned* __restrict__ QDb, const uint2* __restrict__ KV,
    const unsigned short* __restrict__ EBs,
    const int* __restrict__ offsets, const int* __restrict__ srcs,
    float* __restrict__ agg, int n)
{
  int wv = threadIdx.x >> 6, lane = threadIdx.x & 63;
  int node = blockIdx.x*4 + wv;
  if (node >= n) return;
  unsigned qt = QDb[(size_t)node*64 + lane];
  float q0 = bflo(qt) * 0.25f;
  float q1 = bfhi(qt) * 0.25f;
  int beg = offsets[node], end = offsets[node+1];
  int hoff = lane >> 3;
  float acc0 = 0.f, acc1 = 0.f, den = 0.f;
  for (int base = beg; base < end; base += 64) {
    int mrem = end - base; if (mrem > 64) mrem = 64;
    int ss = (lane < mrem) ? srcs[base + lane] : 0;
    int j = 0;
    for (; j + 4 <= mrem; j += 4) {
      int s0 = __shfl(ss, j);
      int s1 = __shfl(ss, j+1);
      int s2 = __shfl(ss, j+2);
      int s3 = __shfl(ss, j+3);
      uint2 kv0 = KV[(size_t)s0*64 + lane];
      uint2 kv1 = KV[(size_t)s1*64 + lane];
      uint2 kv2 = KV[(size_t)s2*64 + lane];
      uint2 kv3 = KV[(size_t)s3*64 + lane];
      float p0 = q0*bflo(kv0.x) + q1*bfhi(kv0.x);
      float p1 = q0*bflo(kv1.x) + q1*bfhi(kv1.x);
      float p2 = q0*bflo(kv2.x) + q1*bfhi(kv2.x);
      float p3 = q0*bflo(kv3.x) + q1*bfhi(kv3.x);
      p0 += __shfl_xor(p0, 1); p1 += __shfl_xor(p1, 1); p2 += __shfl_xor(p2, 1); p3 += __shfl_xor(p3, 1);
      p0 += __shfl_xor(p0, 2); p1 += __shfl_xor(p1, 2); p2 += __shfl_xor(p2, 2); p3 += __shfl_xor(p3, 2);
      p0 += __shfl_xor(p0, 4); p1 += __shfl_xor(p1, 4); p2 += __shfl_xor(p2, 4); p3 += __shfl_xor(p3, 4);
      float eb0 = __uint_as_float(((unsigned)EBs[(size_t)(base+j  )*8 + hoff]) << 16);
      float eb1 = __uint_as_float(((unsigned)EBs[(size_t)(base+j+1)*8 + hoff]) << 16);
      float eb2 = __uint_as_float(((unsigned)EBs[(size_t)(base+j+2)*8 + hoff]) << 16);
      float eb3 = __uint_as_float(((unsigned)EBs[(size_t)(base+j+3)*8 + hoff]) << 16);
      float w0 = __expf(p0 + eb0);    // softmax shift-invariant; fp32 exp safe (|s| small)
      float w1 = __expf(p1 + eb1);
      float w2 = __expf(p2 + eb2);
      float w3 = __expf(p3 + eb3);
      acc0 += w0*bflo(kv0.y) + w1*bflo(kv1.y) + w2*bflo(kv2.y) + w3*bflo(kv3.y);
      acc1 += w0*bfhi(kv0.y) + w1*bfhi(kv1.y) + w2*bfhi(kv2.y) + w3*bfhi(kv3.y);
      den  += (w0 + w1) + (w2 + w3);
    }
    for (; j < mrem; ++j) {
      int s0 = __shfl(ss, j);
      uint2 kv0 = KV[(size_t)s0*64 + lane];
      float p0 = q0*bflo(kv0.x) + q1*bfhi(kv0.x);
      p0 += __shfl_xor(p0, 1);
      p0 += __shfl_xor(p0, 2);
      p0 += __shfl_xor(p0, 4);
      float eb0 = __uint_as_float(((unsigned)EBs[(size_t)(base+j)*8 + hoff]) << 16);
      float w0 = __expf(p0 + eb0);
      acc0 += w0*bflo(kv0.y);
      acc1 += w0*bfhi(kv0.y);
      den  += w0;
    }
  }
  float inv = den > 0.f ? 1.f/den : 0.f;
  float2 o; o.x = acc0*inv; o.y = acc1*inv;
  *(float2*)(agg + (size_t)node*128 + 2*lane) = o;
}

// ---------------- batch-norm finalize / apply ----------------
__global__ void bnfin_k(const float* sum, const float* sq, const float* g,
                        const float* bt, float* scale, float* shift, int M){
  int c = threadIdx.x;
  float mu  = sum[c] / (float)M;
  float var = sq[c] / (float)M - mu*mu;
  float s = g[c] * rsqrtf(var + EPSbn);
  scale[c] = s;
  shift[c] = bt[c] - mu*s;
}

__global__ void bnapply_k(const float* __restrict__ Y, const float* __restrict__ scale,
                          const float* __restrict__ shift, float* __restrict__ out, int total){
  int n4 = total >> 2;
  for (int i = blockIdx.x*blockDim.x + threadIdx.x; i < n4; i += gridDim.x*blockDim.x) {
    float4 vv = ((const float4*)Y)[i];
    int c = (i << 2) & 127;
    vv.x = vv.x*scale[c  ] + shift[c  ];
    vv.y = vv.y*scale[c+1] + shift[c+1];
    vv.z = vv.z*scale[c+2] + shift[c+2];
    vv.w = vv.w*scale[c+3] + shift[c+3];
    ((float4*)out)[i] = vv;
  }
}

extern "C" void kernel_launch(void* const* d_in, const int* in_sizes, int n_in,
                              void* d_out, int out_size, void* d_ws, size_t ws_size,
                              hipStream_t stream) {
  const float* q   = (const float*)d_in[0];
  const float* k   = (const float*)d_in[1];
  const float* v   = (const float*)d_in[2];
  const float* ef  = (const float*)d_in[3];
  const int*   src = (const int*)d_in[4];
  const int*   dst = (const int*)d_in[5];
  const float* Wq  = (const float*)d_in[6];
  const float* Wk  = (const float*)d_in[7];
  const float* Wv  = (const float*)d_in[8];
  const float* We  = (const float*)d_in[9];
  const float* be  = (const float*)d_in[10];
  const float* Wo  = (const float*)d_in[11];
  const float* W1  = (const float*)d_in[12];
  const float* b1  = (const float*)d_in[13];
  const float* W2  = (const float*)d_in[14];
  const float* b2  = (const float*)d_in[15];
  const float* g1  = (const float*)d_in[16];
  const float* bt1 = (const float*)d_in[17];
  const float* g2  = (const float*)d_in[18];
  const float* bt2 = (const float*)d_in[19];
  float* out = (float*)d_out;

  // ---- workspace layout (float units); NB = N*128 = 5.12M ----
  // [0,     NB/2)   QDb bf16 [N,128]          } H1 bf16 [N,256] overlays [0,NB)
  // [NB/2,  3NB/2)  KV  bf16 [N,256] interleaved
  // [3NB/2, 2NB)    EBs bf16 [E,8] (CSR order)
  // [2NB,   3NB)    AGG f32 -> Y f32
  // [3NB,   4NB)    RST f32
  // [4NB, +1024)    bn scratch; ints after (counts contiguous with bn -> one zero)
  float* ws = (float*)d_ws;
  const size_t NB = (size_t)Nn * CC;            // 5,120,000
  float* QDb = ws;
  float* KV  = ws + NB/2;
  unsigned short* EBs = (unsigned short*)(ws + 3*NB/2);
  float* AGG = ws + 2*NB;
  float* RST = ws + 3*NB;
  float* H1  = ws;          // [N,256] bf16 overlays QDb+half of KV (dead by then)
  float* Y   = AGG;
  float* bn = ws + 4*NB;
  float* sum1 = bn;       float* sq1 = bn+128;  float* sc1 = bn+256; float* sh1 = bn+384;
  float* sum2 = bn+512;   float* sq2 = bn+640;  float* sc2 = bn+768; float* sh2 = bn+896;
  int* ib      = (int*)(bn + 1024);
  int* counts  = ib;                    // 40000
  int* offsets = ib + 40000;            // 40001
  int* cursor  = ib + 80001;            // 40000
  int* posA    = ib + 120001;           // 640000
  int* srcsA   = ib + 760001;           // 640000
  int* bsums   = ib + 1400001;          // 64

  // one zero covers bn scratch (1024) + counts (40000) — contiguous
  zero_k<<<dim3(161), 256, 0, stream>>>((int*)bn, 1024 + Nn);

  // CSR build
  hist_k<<<dim3(2500), 256, 0, stream>>>(dst, counts, Ne);
  scan1_k<<<dim3(40), 256, 0, stream>>>(counts, offsets, bsums, Nn);
  scan2_k<<<dim3(1), 64, 0, stream>>>(bsums, 40);
  scan3_k<<<dim3(157), 256, 0, stream>>>(offsets, bsums, cursor, Nn, Ne);
  scatter_k<<<dim3(2500), 256, 0, stream>>>(dst, src, cursor, posA, srcsA, Ne);

  // projections (merged, z=3): QDb bf16 | KV K-phase | KV V-phase
  {
    GA3 ga;
    ga.A0 = q;  ga.A1 = k;  ga.A2 = v;
    ga.W0 = Wq; ga.W1 = Wk; ga.W2 = Wv;
    ga.C0 = QDb; ga.C1 = KV; ga.C2 = KV;
    ga.m0 = 1; ga.m1 = 2; ga.m2 = 3;
    mgemm_k<1,false,false,false,false,false,false,false><<<dim3(313,1,3),256,0,stream>>>(
        ga, nullptr, nullptr, nullptr, nullptr, nullptr, nullptr, Nn, 128);
  }

  // per-edge bias, CSR order
  ebias_k<<<dim3(Ne/32), 256, 0, stream>>>(ef, We, be, posA, EBs);

  // fused scores + segment softmax + aggregation
  agg_k<<<dim3(Nn/4), 256, 0, stream>>>((const unsigned*)QDb, (const uint2*)KV, EBs,
                                        offsets, srcsA, AGG, Nn);

  // RST = AGG@Wo^T + q   (+ fused BN1 stats)
  {
    GA3 ga = {};
    ga.A0 = AGG; ga.W0 = Wo; ga.C0 = RST; ga.m0 = 0;
    mgemm_k<1,false,false,true,false,false,false,true><<<dim3(313,1,1),256,0,stream>>>(
        ga, nullptr, q, nullptr, nullptr, sum1, sq1, Nn, 128);
  }
  bnfin_k<<<dim3(1), 128, 0, stream>>>(sum1, sq1, g1, bt1, sc1, sh1, Nn);

  // FFN1: H1 = relu(bn1(RST)@W1^T + b1)  [N,256] bf16
  {
    GA3 ga = {};
    ga.A0 = RST; ga.W0 = W1; ga.C0 = H1; ga.m0 = 1;
    mgemm_k<1,false,true,false,true,true,false,false><<<dim3(313,2,1),256,0,stream>>>(
        ga, b1, nullptr, sc1, sh1, nullptr, nullptr, Nn, 256);
  }

  // FFN2: Y = H1@W2^T + b2 + bn1(RST)    [N,128] f32  (+ fused BN2 stats)
  {
    GA3 ga = {};
    ga.A0 = H1; ga.W0 = W2; ga.C0 = Y; ga.m0 = 0;
    mgemm_k<2,true,true,true,false,false,true,true><<<dim3(313,1,1),256,0,stream>>>(
        ga, b2, RST, sc1, sh1, sum2, sq2, Nn, 128);
  }
  bnfin_k<<<dim3(1), 128, 0, stream>>>(sum2, sq2, g2, bt2, sc2, sh2, Nn);
  bnapply_k<<<dim3(1024), 256, 0, stream>>>(Y, sc2, sh2, out, Nn*CC);
}

// Round 5
// 543.714 us; speedup vs baseline: 1.0563x; 1.0563x over previous
//
#include <hip/hip_runtime.h>
#include <cstdint>
#include <cstddef>

#define Nn 40000
#define Ne 640000
#define CC 128
#define EPSbn 1e-5f

typedef __attribute__((ext_vector_type(8))) __bf16 bf16x8;
typedef __attribute__((ext_vector_type(4))) float floatx4;

__device__ inline unsigned short f2bf(float x){
  union { float f; unsigned u; } c; c.f = x;
  unsigned r = c.u + 0x7fffu + ((c.u >> 16) & 1u);
  return (unsigned short)(r >> 16);
}
__device__ inline float bflo(unsigned u){ return __uint_as_float(u << 16); }
__device__ inline float bfhi(unsigned u){ return __uint_as_float(u & 0xffff0000u); }

// ---- fp8 e4m3fn encode (manual RNE; encode is cold-path, repack kernel only) ----
__device__ inline unsigned f2e4m3(float x){
  unsigned u = __float_as_uint(x);
  unsigned s = (u >> 24) & 0x80u;
  unsigned a = u & 0x7fffffffu;
  unsigned lsb = (a >> 20) & 1u;
  a += 0x0007FFFFu + lsb;                  // RNE to 3 mantissa bits
  int e = (int)((a >> 23) & 0xffu) - 127;
  unsigned b;
  if (e < -9)      b = 0u;
  else if (e < -6) b = (unsigned)(int)rintf(__uint_as_float(u & 0x7fffffffu) * 512.f);
  else if (e > 8)  b = 0x7Eu;
  else             b = (unsigned)(((e + 7) << 3) | ((a >> 20) & 7u));
  if ((b & 0x7fu) == 0x7fu) b = 0x7Eu;     // avoid NaN encoding (e4m3fn)
  return s | b;
}

// ---- fp8 e4m3fn decode: HW builtin (1 op) with guarded fallback ----
#if defined(__has_builtin)
#if __has_builtin(__builtin_amdgcn_cvt_f32_fp8)
#define FP8_HW 1
#endif
#endif
template<int SEL>
__device__ inline float fp8dec(unsigned w){
#ifdef FP8_HW
  return __builtin_amdgcn_cvt_f32_fp8((int)w, SEL);
#else
  unsigned b = (w >> (SEL*8)) & 0xffu;
  unsigned s = (b & 0x80u) << 24;
  unsigned em = b & 0x7fu;
  float v;
  if (em >= 8) v = __uint_as_float((((em >> 3) + 117u) << 23)) * (float)(8 + (em & 7));
  else         v = (float)em * 0.001953125f;   // em * 2^-9
  return __uint_as_float(__float_as_uint(v) | s);
#endif
}

// ---------------- zero ----------------
__global__ void zero_k(int* __restrict__ p, int n){
  int i = blockIdx.x*blockDim.x + threadIdx.x;
  if (i < n) p[i] = 0;
}

// ---------------- MFMA bf16 GEMM (z-batched): C = act(A' @ W^T + bias + res') ----------------
// mode: 0 = f32 out, 1 = bf16 out
struct GA3 {
  const void* A0; const void* A1; const void* A2;
  const float* W0; const float* W1; const float* W2;
  void* C0; void* C1; void* C2;
  int m0, m1, m2;
};

template<int KTILES,bool ABF16,bool HASBIAS,bool HASRES,bool RELU,bool AFFA,bool AFFRES,bool BNSTAT>
__global__ __launch_bounds__(256,2) void mgemm_k(
    GA3 ga, const float* __restrict__ bias, const float* __restrict__ res,
    const float* __restrict__ sc, const float* __restrict__ sh,
    float* __restrict__ bnS, float* __restrict__ bnQ,
    int M, int Ncols)
{
  constexpr int K = KTILES * 128;
  __shared__ __align__(16) unsigned short As[128*136];  // +8 pad: 2-way alias (free)
  __shared__ __align__(16) unsigned short Ws[128*136];
  const int z = blockIdx.z;
  const void*  Ap = (z==0) ? ga.A0 : (z==1) ? ga.A1 : ga.A2;
  const float* W  = (z==0) ? ga.W0 : (z==1) ? ga.W1 : ga.W2;
  void*        Cp = (z==0) ? ga.C0 : (z==1) ? ga.C1 : ga.C2;
  const int mode  = (z==0) ? ga.m0 : (z==1) ? ga.m1 : ga.m2;

  const int tid  = threadIdx.x;
  const int lane = tid & 63;
  const int wv   = tid >> 6;
  const int m    = lane & 15;
  const int quad = lane >> 4;
  const int row0 = blockIdx.x * 128;
  const int col0 = blockIdx.y * 128;
  floatx4 acc[2][8] = {};

  for (int kt = 0; kt < K; kt += 128) {
    #pragma unroll 4
    for (int it = 0; it < 16; ++it) {
      int s = tid + it*256;        // 0..4095
      int r = s >> 5;              // 0..127
      int c = (s & 31) << 2;       // 0..124
      int gr = row0 + r; if (gr >= M) gr = M - 1;
      ushort4 ua;
      if (ABF16) {
        ua = *(const ushort4*)((const unsigned short*)Ap + (size_t)gr*K + kt + c);
      } else {
        float4 a4 = *(const float4*)((const float*)Ap + (size_t)gr*K + kt + c);
        if (AFFA) {
          int kk = kt + c;
          a4.x = a4.x*sc[kk  ] + sh[kk  ];
          a4.y = a4.y*sc[kk+1] + sh[kk+1];
          a4.z = a4.z*sc[kk+2] + sh[kk+2];
          a4.w = a4.w*sc[kk+3] + sh[kk+3];
        }
        ua.x = f2bf(a4.x); ua.y = f2bf(a4.y); ua.z = f2bf(a4.z); ua.w = f2bf(a4.w);
      }
      *(ushort4*)&As[r*136 + c] = ua;
      float4 w4 = *(const float4*)(W + (size_t)(col0 + r)*K + kt + c);
      ushort4 uw;
      uw.x = f2bf(w4.x); uw.y = f2bf(w4.y); uw.z = f2bf(w4.z); uw.w = f2bf(w4.w);
      *(ushort4*)&Ws[r*136 + c] = uw;
    }
    __syncthreads();
    #pragma unroll
    for (int ks = 0; ks < 4; ++ks) {
      int ko = ks*32 + quad*8;
      bf16x8 a0 = *(const bf16x8*)&As[(32*wv      + m)*136 + ko];
      bf16x8 a1 = *(const bf16x8*)&As[(32*wv + 16 + m)*136 + ko];
      #pragma unroll
      for (int j = 0; j < 8; ++j) {
        bf16x8 bj = *(const bf16x8*)&Ws[(16*j + m)*136 + ko];
        acc[0][j] = __builtin_amdgcn_mfma_f32_16x16x32_bf16(a0, bj, acc[0][j], 0, 0, 0);
        acc[1][j] = __builtin_amdgcn_mfma_f32_16x16x32_bf16(a1, bj, acc[1][j], 0, 0, 0);
      }
    }
    __syncthreads();
  }

  float bcol[8], scv[8], shv[8];
  #pragma unroll
  for (int j = 0; j < 8; ++j) {
    int gcol = col0 + 16*j + m;
    if (HASBIAS) bcol[j] = bias[gcol];
    if (AFFRES) { scv[j] = sc[gcol]; shv[j] = sh[gcol]; }
  }
  float ps[8] = {}, pq[8] = {};
  #pragma unroll
  for (int rt = 0; rt < 2; ++rt) {
    #pragma unroll
    for (int rg = 0; rg < 4; ++rg) {
      int grow = row0 + 32*wv + 16*rt + quad*4 + rg;
      if (grow < M) {
        #pragma unroll
        for (int j = 0; j < 8; ++j) {
          int gcol = col0 + 16*j + m;
          float o = acc[rt][j][rg];
          if (HASBIAS) o += bcol[j];
          if (HASRES) {
            float rr = res[(size_t)grow*Ncols + gcol];
            if (AFFRES) rr = rr*scv[j] + shv[j];
            o += rr;
          }
          if (RELU) o = fmaxf(o, 0.f);
          if (BNSTAT) { ps[j] += o; pq[j] += o*o; }
          if (mode == 0) ((float*)Cp)[(size_t)grow*Ncols + gcol] = o;
          else           ((unsigned short*)Cp)[(size_t)grow*Ncols + gcol] = f2bf(o);
        }
      }
    }
  }
  if (BNSTAT) {
    float* sS = (float*)&As[0];        // reuse LDS: 4 waves x 128 cols
    float* sQ = sS + 4*128;
    #pragma unroll
    for (int j = 0; j < 8; ++j) {
      float s = ps[j], qq = pq[j];
      s += __shfl_xor(s, 16); qq += __shfl_xor(qq, 16);
      s += __shfl_xor(s, 32); qq += __shfl_xor(qq, 32);
      if (quad == 0) { sS[wv*128 + 16*j + m] = s; sQ[wv*128 + 16*j + m] = qq; }
    }
    __syncthreads();
    if (wv == 0) {
      #pragma unroll
      for (int c = 0; c < 128; c += 64) {
        int cc = c + lane;
        float s  = sS[cc] + sS[128+cc] + sS[256+cc] + sS[384+cc];
        float qq = sQ[cc] + sQ[128+cc] + sQ[256+cc] + sQ[384+cc];
        atomicAdd(&bnS[col0 + cc], s);
        atomicAdd(&bnQ[col0 + cc], qq);
      }
    }
  }
}

// ---------------- bf16 K,V -> fp8 packed KV (one dword per channel-pair) ----------------
// KV[n][d] bytes: [K[2d], K[2d+1], V[2d], V[2d+1]]  (d = 0..63)
__global__ __launch_bounds__(256) void repack_k(
    const unsigned* __restrict__ Kb, const unsigned* __restrict__ Vb,
    unsigned* __restrict__ KV, int total)
{
  int i = blockIdx.x*blockDim.x + threadIdx.x;
  if (i < total) {
    unsigned kk = Kb[i];
    unsigned vv = Vb[i];
    unsigned o = f2e4m3(bflo(kk)) | (f2e4m3(bfhi(kk)) << 8)
               | (f2e4m3(bflo(vv)) << 16) | (f2e4m3(bfhi(vv)) << 24);
    KV[i] = o;
  }
}

// ---------------- per-edge bias -> CSR-ordered bf16 table ----------------
__global__ __launch_bounds__(256) void ebias_k(
    const float* __restrict__ ef, const float* __restrict__ We,
    const float* __restrict__ be, const int* __restrict__ pos,
    unsigned short* __restrict__ EBs)
{
  __shared__ float efs[32][68];
  __shared__ float Wes[8][68];
  __shared__ float bes[8];
  int tid = threadIdx.x;
  if (tid < 8) bes[tid] = be[tid];
  for (int i = tid; i < 512; i += 256) Wes[i>>6][i&63] = We[i];
  int e0 = blockIdx.x * 32;
  #pragma unroll
  for (int l = 0; l < 2; ++l) {
    int idx = tid + l*256;
    int r   = idx >> 4;
    int q4  = (idx & 15) << 2;
    float4 t = *(const float4*)(ef + (size_t)(e0 + r)*64 + q4);
    efs[r][q4]=t.x; efs[r][q4+1]=t.y; efs[r][q4+2]=t.z; efs[r][q4+3]=t.w;
  }
  __syncthreads();
  int h = tid & 7, el = tid >> 3;
  int e = e0 + el;
  float es = 0.f;
  #pragma unroll
  for (int kk = 0; kk < 64; kk += 4) {
    float4 a = *(const float4*)&efs[el][kk];
    float4 b = *(const float4*)&Wes[h][kk];
    es += a.x*b.x + a.y*b.y + a.z*b.z + a.w*b.w;
  }
  EBs[(size_t)pos[e]*8 + h] = f2bf(es + bes[h]);
}

// ---------------- CSR build ----------------
__global__ void hist_k(const int* __restrict__ dst, int* __restrict__ counts, int E){
  int i = blockIdx.x*blockDim.x + threadIdx.x;
  if (i < E) atomicAdd(&counts[dst[i]], 1);
}

__global__ __launch_bounds__(256) void scan1_k(
    const int* __restrict__ counts, int* __restrict__ part,
    int* __restrict__ bsums, int n)
{
  int tid = threadIdx.x;
  int base = blockIdx.x*1024 + tid*4;
  int v0 = (base   < n) ? counts[base  ] : 0;
  int v1 = (base+1 < n) ? counts[base+1] : 0;
  int v2 = (base+2 < n) ? counts[base+2] : 0;
  int v3 = (base+3 < n) ? counts[base+3] : 0;
  int t1 = v0+v1, t2 = t1+v2, t3 = t2+v3;
  int lane = tid & 63, wv = tid >> 6;
  int x = t3;
  #pragma unroll
  for (int off = 1; off < 64; off <<= 1) {
    int y = __shfl_up(x, off);
    if (lane >= off) x += y;
  }
  __shared__ int wt[4];
  if (lane == 63) wt[wv] = x;
  __syncthreads();
  int wbase = 0;
  #pragma unroll
  for (int w = 0; w < 4; ++w) if (w < wv) wbase += wt[w];
  int excl = wbase + x - t3;
  if (base   < n) part[base  ] = excl;
  if (base+1 < n) part[base+1] = excl + v0;
  if (base+2 < n) part[base+2] = excl + t1;
  if (base+3 < n) part[base+3] = excl + t2;
  if (tid == 255) bsums[blockIdx.x] = wbase + x;
}

__global__ void scan2_k(int* bsums, int nb){
  int lane = threadIdx.x;
  int v = (lane < nb) ? bsums[lane] : 0;
  int x = v;
  #pragma unroll
  for (int off = 1; off < 64; off <<= 1) {
    int y = __shfl_up(x, off);
    if (lane >= off) x += y;
  }
  if (lane < nb) bsums[lane] = x - v;   // exclusive
}

__global__ void scan3_k(int* __restrict__ offsets, const int* __restrict__ bsums,
                        int* __restrict__ cursor, int n, int E){
  int i = blockIdx.x*blockDim.x + threadIdx.x;
  if (i < n) {
    int o = offsets[i] + bsums[i >> 10];
    offsets[i] = o;
    cursor[i]  = o;
  }
  if (i == 0) offsets[n] = E;
}

__global__ void scatter_k(const int* __restrict__ dst, const int* __restrict__ src,
                          int* __restrict__ cursor, int* __restrict__ pos,
                          int* __restrict__ srcs, int E){
  int i = blockIdx.x*blockDim.x + threadIdx.x;
  if (i < E) {
    int p = atomicAdd(&cursor[dst[i]], 1);
    pos[i]  = p;
    srcs[p] = src[i];
  }
}

// ---------------- fused scores + segment softmax + aggregation ----------------
// One wave per dst node; lane l holds channels {2l,2l+1}; head = l>>3.
// KV row: dword l = fp8 [K2l, K2l+1, V2l, V2l+1]  (256 B/row = one cache line).
__global__ __launch_bounds__(256) void agg_k(
    const unsigned* __restrict__ QDb, const unsigned* __restrict__ KV,
    const unsigned short* __restrict__ EBs,
    const int* __restrict__ offsets, const int* __restrict__ srcs,
    float* __restrict__ agg, int n)
{
  int wv = threadIdx.x >> 6, lane = threadIdx.x & 63;
  int node = blockIdx.x*4 + wv;
  if (node >= n) return;
  unsigned qt = QDb[(size_t)node*64 + lane];
  float q0 = bflo(qt) * 0.25f;
  float q1 = bfhi(qt) * 0.25f;
  int beg = offsets[node], end = offsets[node+1];
  int hoff = lane >> 3;
  float acc0 = 0.f, acc1 = 0.f, den = 0.f;
  for (int base = beg; base < end; base += 64) {
    int mrem = end - base; if (mrem > 64) mrem = 64;
    int ss = (lane < mrem) ? srcs[base + lane] : 0;
    int j = 0;
    for (; j + 4 <= mrem; j += 4) {
      int s0 = __shfl(ss, j);
      int s1 = __shfl(ss, j+1);
      int s2 = __shfl(ss, j+2);
      int s3 = __shfl(ss, j+3);
      unsigned kv0 = KV[(size_t)s0*64 + lane];
      unsigned kv1 = KV[(size_t)s1*64 + lane];
      unsigned kv2 = KV[(size_t)s2*64 + lane];
      unsigned kv3 = KV[(size_t)s3*64 + lane];
      float p0 = q0*fp8dec<0>(kv0) + q1*fp8dec<1>(kv0);
      float p1 = q0*fp8dec<0>(kv1) + q1*fp8dec<1>(kv1);
      float p2 = q0*fp8dec<0>(kv2) + q1*fp8dec<1>(kv2);
      float p3 = q0*fp8dec<0>(kv3) + q1*fp8dec<1>(kv3);
      p0 += __shfl_xor(p0, 1); p1 += __shfl_xor(p1, 1); p2 += __shfl_xor(p2, 1); p3 += __shfl_xor(p3, 1);
      p0 += __shfl_xor(p0, 2); p1 += __shfl_xor(p1, 2); p2 += __shfl_xor(p2, 2); p3 += __shfl_xor(p3, 2);
      p0 += __shfl_xor(p0, 4); p1 += __shfl_xor(p1, 4); p2 += __shfl_xor(p2, 4); p3 += __shfl_xor(p3, 4);
      float eb0 = __uint_as_float(((unsigned)EBs[(size_t)(base+j  )*8 + hoff]) << 16);
      float eb1 = __uint_as_float(((unsigned)EBs[(size_t)(base+j+1)*8 + hoff]) << 16);
      float eb2 = __uint_as_float(((unsigned)EBs[(size_t)(base+j+2)*8 + hoff]) << 16);
      float eb3 = __uint_as_float(((unsigned)EBs[(size_t)(base+j+3)*8 + hoff]) << 16);
      float w0 = __expf(p0 + eb0);    // softmax shift-invariant; fp32 exp safe (|s| small)
      float w1 = __expf(p1 + eb1);
      float w2 = __expf(p2 + eb2);
      float w3 = __expf(p3 + eb3);
      acc0 += w0*fp8dec<2>(kv0) + w1*fp8dec<2>(kv1) + w2*fp8dec<2>(kv2) + w3*fp8dec<2>(kv3);
      acc1 += w0*fp8dec<3>(kv0) + w1*fp8dec<3>(kv1) + w2*fp8dec<3>(kv2) + w3*fp8dec<3>(kv3);
      den  += (w0 + w1) + (w2 + w3);
    }
    for (; j < mrem; ++j) {
      int s0 = __shfl(ss, j);
      unsigned kv0 = KV[(size_t)s0*64 + lane];
      float p0 = q0*fp8dec<0>(kv0) + q1*fp8dec<1>(kv0);
      p0 += __shfl_xor(p0, 1);
      p0 += __shfl_xor(p0, 2);
      p0 += __shfl_xor(p0, 4);
      float eb0 = __uint_as_float(((unsigned)EBs[(size_t)(base+j)*8 + hoff]) << 16);
      float w0 = __expf(p0 + eb0);
      acc0 += w0*fp8dec<2>(kv0);
      acc1 += w0*fp8dec<3>(kv0);
      den  += w0;
    }
  }
  float inv = den > 0.f ? 1.f/den : 0.f;
  float2 o; o.x = acc0*inv; o.y = acc1*inv;
  *(float2*)(agg + (size_t)node*128 + 2*lane) = o;
}

// ---------------- batch-norm finalize / apply ----------------
__global__ void bnfin_k(const float* sum, const float* sq, const float* g,
                        const float* bt, float* scale, float* shift, int M){
  int c = threadIdx.x;
  float mu  = sum[c] / (float)M;
  float var = sq[c] / (float)M - mu*mu;
  float s = g[c] * rsqrtf(var + EPSbn);
  scale[c] = s;
  shift[c] = bt[c] - mu*s;
}

__global__ void bnapply_k(const float* __restrict__ Y, const float* __restrict__ scale,
                          const float* __restrict__ shift, float* __restrict__ out, int total){
  int n4 = total >> 2;
  for (int i = blockIdx.x*blockDim.x + threadIdx.x; i < n4; i += gridDim.x*blockDim.x) {
    float4 vv = ((const float4*)Y)[i];
    int c = (i << 2) & 127;
    vv.x = vv.x*scale[c  ] + shift[c  ];
    vv.y = vv.y*scale[c+1] + shift[c+1];
    vv.z = vv.z*scale[c+2] + shift[c+2];
    vv.w = vv.w*scale[c+3] + shift[c+3];
    ((float4*)out)[i] = vv;
  }
}

extern "C" void kernel_launch(void* const* d_in, const int* in_sizes, int n_in,
                              void* d_out, int out_size, void* d_ws, size_t ws_size,
                              hipStream_t stream) {
  const float* q   = (const float*)d_in[0];
  const float* k   = (const float*)d_in[1];
  const float* v   = (const float*)d_in[2];
  const float* ef  = (const float*)d_in[3];
  const int*   src = (const int*)d_in[4];
  const int*   dst = (const int*)d_in[5];
  const float* Wq  = (const float*)d_in[6];
  const float* Wk  = (const float*)d_in[7];
  const float* Wv  = (const float*)d_in[8];
  const float* We  = (const float*)d_in[9];
  const float* be  = (const float*)d_in[10];
  const float* Wo  = (const float*)d_in[11];
  const float* W1  = (const float*)d_in[12];
  const float* b1  = (const float*)d_in[13];
  const float* W2  = (const float*)d_in[14];
  const float* b2  = (const float*)d_in[15];
  const float* g1  = (const float*)d_in[16];
  const float* bt1 = (const float*)d_in[17];
  const float* g2  = (const float*)d_in[18];
  const float* bt2 = (const float*)d_in[19];
  float* out = (float*)d_out;

  // ---- workspace layout (float units); NB = N*128 = 5.12M ----
  // [0,      NB/2)   QDb bf16 [N,128]   } H1 bf16 [N,256] overlays [0,NB)
  // [NB/2,   NB)     Kb  bf16 [N,128]   }
  // [NB,     3NB/2)  Vb  bf16 [N,128]
  // [3NB/2,  2NB)    KVq fp8  [N,64] dwords
  // [2NB,    5NB/2)  EBs bf16 [E,8] (CSR order)
  // [5NB/2,  7NB/2)  AGG f32 -> Y f32
  // [7NB/2,  9NB/2)  RST f32
  // [9NB/2, +1024)   bn scratch; ints after (counts contiguous -> one zero)
  float* ws = (float*)d_ws;
  const size_t NB = (size_t)Nn * CC;            // 5,120,000
  float* QDb = ws;
  float* Kb  = ws + NB/2;
  float* Vb  = ws + NB;
  unsigned* KVq = (unsigned*)(ws + 3*NB/2);
  unsigned short* EBs = (unsigned short*)(ws + 2*NB);
  float* AGG = ws + 5*NB/2;
  float* RST = ws + 7*NB/2;
  float* H1  = ws;          // [N,256] bf16 overlays QDb+Kb (dead by FFN1)
  float* Y   = AGG;
  float* bn = ws + 9*NB/2;
  float* sum1 = bn;       float* sq1 = bn+128;  float* sc1 = bn+256; float* sh1 = bn+384;
  float* sum2 = bn+512;   float* sq2 = bn+640;  float* sc2 = bn+768; float* sh2 = bn+896;
  int* ib      = (int*)(bn + 1024);
  int* counts  = ib;                    // 40000
  int* offsets = ib + 40000;            // 40001
  int* cursor  = ib + 80001;            // 40000
  int* posA    = ib + 120001;           // 640000
  int* srcsA   = ib + 760001;           // 640000
  int* bsums   = ib + 1400001;          // 64

  // one zero covers bn scratch (1024) + counts (40000) — contiguous
  zero_k<<<dim3(161), 256, 0, stream>>>((int*)bn, 1024 + Nn);

  // CSR build
  hist_k<<<dim3(2500), 256, 0, stream>>>(dst, counts, Ne);
  scan1_k<<<dim3(40), 256, 0, stream>>>(counts, offsets, bsums, Nn);
  scan2_k<<<dim3(1), 64, 0, stream>>>(bsums, 40);
  scan3_k<<<dim3(157), 256, 0, stream>>>(offsets, bsums, cursor, Nn, Ne);
  scatter_k<<<dim3(2500), 256, 0, stream>>>(dst, src, cursor, posA, srcsA, Ne);

  // projections (merged, z=3): QDb / Kb / Vb, all bf16 row-major (coalesced stores)
  {
    GA3 ga;
    ga.A0 = q;  ga.A1 = k;  ga.A2 = v;
    ga.W0 = Wq; ga.W1 = Wk; ga.W2 = Wv;
    ga.C0 = QDb; ga.C1 = Kb; ga.C2 = Vb;
    ga.m0 = 1; ga.m1 = 1; ga.m2 = 1;
    mgemm_k<1,false,false,false,false,false,false,false><<<dim3(313,1,3),256,0,stream>>>(
        ga, nullptr, nullptr, nullptr, nullptr, nullptr, nullptr, Nn, 128);
  }

  // bf16 K,V -> packed fp8 KV (streaming, 30 MB)
  repack_k<<<dim3(10000), 256, 0, stream>>>((const unsigned*)Kb, (const unsigned*)Vb,
                                            KVq, Nn*64);

  // per-edge bias, CSR order
  ebias_k<<<dim3(Ne/32), 256, 0, stream>>>(ef, We, be, posA, EBs);

  // fused scores + segment softmax + aggregation (fp8 KV gather: 256 B/edge)
  agg_k<<<dim3(Nn/4), 256, 0, stream>>>((const unsigned*)QDb, KVq, EBs,
                                        offsets, srcsA, AGG, Nn);

  // RST = AGG@Wo^T + q   (+ fused BN1 stats)
  {
    GA3 ga = {};
    ga.A0 = AGG; ga.W0 = Wo; ga.C0 = RST; ga.m0 = 0;
    mgemm_k<1,false,false,true,false,false,false,true><<<dim3(313,1,1),256,0,stream>>>(
        ga, nullptr, q, nullptr, nullptr, sum1, sq1, Nn, 128);
  }
  bnfin_k<<<dim3(1), 128, 0, stream>>>(sum1, sq1, g1, bt1, sc1, sh1, Nn);

  // FFN1: H1 = relu(bn1(RST)@W1^T + b1)  [N,256] bf16
  {
    GA3 ga = {};
    ga.A0 = RST; ga.W0 = W1; ga.C0 = H1; ga.m0 = 1;
    mgemm_k<1,false,true,false,true,true,false,false><<<dim3(313,2,1),256,0,stream>>>(
        ga, b1, nullptr, sc1, sh1, nullptr, nullptr, Nn, 256);
  }

  // FFN2: Y = H1@W2^T + b2 + bn1(RST)    [N,128] f32  (+ fused BN2 stats)
  {
    GA3 ga = {};
    ga.A0 = H1; ga.W0 = W2; ga.C0 = Y; ga.m0 = 0;
    mgemm_k<2,true,true,true,false,false,true,true><<<dim3(313,1,1),256,0,stream>>>(
        ga, b2, RST, sc1, sh1, sum2, sq2, Nn, 128);
  }
  bnfin_k<<<dim3(1), 128, 0, stream>>>(sum2, sq2, g2, bt2, sc2, sh2, Nn);
  bnapply_k<<<dim3(1024), 256, 0, stream>>>(Y, sc2, sh2, out, Nn*CC);
}